// Round 2
// 137.175 us; speedup vs baseline: 1.0633x; 1.0633x over previous
//
#include <hip/hip_runtime.h>
#include <hip/hip_bf16.h>

#define B_ 8
#define T_ 2048
#define E_ 1024
#define D_ 128

typedef __attribute__((ext_vector_type(8))) short short8;
typedef __attribute__((ext_vector_type(4))) short short4v;
typedef __attribute__((ext_vector_type(4))) float floatx4;
typedef __attribute__((ext_vector_type(16))) float floatx16;
typedef __attribute__((ext_vector_type(2))) unsigned int uint2v;

__device__ __forceinline__ unsigned short f2b(float f) {
  union { float f; unsigned int u; } v; v.f = f;
  unsigned int u = v.u;
  return (unsigned short)((u + 0x7fffu + ((u >> 16) & 1u)) >> 16);  // RNE
}

// v_cvt_pk_bf16_f32: lo16 = bf16(a), hi16 = bf16(b), RNE (same as f2b).
__device__ __forceinline__ unsigned int cvtpk_bf16(float a, float b) {
  unsigned int r;
  asm("v_cvt_pk_bf16_f32 %0, %1, %2" : "=v"(r) : "v"(a), "v"(b));
  return r;
}

#if defined(__has_builtin)
#if __has_builtin(__builtin_amdgcn_permlane32_swap)
#define HAVE_PL32 1
#endif
#endif

// Swap: a[32+i] <-> b[i]. Builtin returns {new_a, new_b} (compiler-managed
// registers — r8's inline-asm tied-operand version produced garbage mx).
#if defined(HAVE_PL32)
#define PLSWAP(a, b)                                                         \
  {                                                                          \
    auto _r = __builtin_amdgcn_permlane32_swap((a), (b), false, false);      \
    (a) = (unsigned int)_r[0];                                               \
    (b) = (unsigned int)_r[1];                                               \
  }
#else
#define PLSWAP(a, b)                                                         \
  {                                                                          \
    unsigned int _pa = (unsigned int)__shfl_xor((int)(b), 32, 64);           \
    unsigned int _pb = (unsigned int)__shfl_xor((int)(a), 32, 64);           \
    if (hi) { (a) = _pa; } else { (b) = _pb; }                               \
  }
#endif

__device__ __forceinline__ float xhalf_max(float x) {
#if defined(HAVE_PL32)
  auto r = __builtin_amdgcn_permlane32_swap(__float_as_uint(x), __float_as_uint(x),
                                            false, false);
  return fmaxf(__uint_as_float((unsigned int)r[0]), __uint_as_float((unsigned int)r[1]));
#else
  return fmaxf(x, __uint_as_float((unsigned int)__shfl_xor(
                      (int)__float_as_uint(x), 32, 64)));
#endif
}

__device__ __forceinline__ float xhalf_sum(float x) {
#if defined(HAVE_PL32)
  auto r = __builtin_amdgcn_permlane32_swap(__float_as_uint(x), __float_as_uint(x),
                                            false, false);
  return __uint_as_float((unsigned int)r[0]) + __uint_as_float((unsigned int)r[1]);
#else
  return x + __uint_as_float((unsigned int)__shfl_xor(
                 (int)__float_as_uint(x), 32, 64));
#endif
}

#if defined(__has_builtin)
#if __has_builtin(__builtin_amdgcn_exp2f)
#define EXP2F(x) __builtin_amdgcn_exp2f(x)
#else
#define EXP2F(x) exp2f(x)
#endif
#else
#define EXP2F(x) exp2f(x)
#endif

__device__ __forceinline__ void gl_lds16(const unsigned short* g, unsigned short* l) {
  __builtin_amdgcn_global_load_lds(
      (const __attribute__((address_space(1))) unsigned int*)g,
      (__attribute__((address_space(3))) unsigned int*)l, 16, 0, 0);
}

// ---------------------------------------------------------------------------
// Kernel 1: W [1024x128] fp32 -> Wt3 [3][128][1024] bf16 via LDS transpose.
// log2e/sqrt(128) folded into Wq (attn softmax then uses exp2 directly).
// ---------------------------------------------------------------------------
__global__ __launch_bounds__(256) void wtrans_kernel(
    const float* __restrict__ Wq, const float* __restrict__ Wk,
    const float* __restrict__ Wv, unsigned short* __restrict__ Wt3) {
  __shared__ __align__(16) unsigned short Tls[32][136];
  const int tid = threadIdx.x;
  const int w = blockIdx.x >> 5;
  const int rem = blockIdx.x & 31;
  const int k0 = (rem >> 2) * 128;
  const int n0 = (rem & 3) * 32;
  const float* W = (w == 0) ? Wq : ((w == 1) ? Wk : Wv);
  const float scale = (w == 0) ? (1.4426950408889634f * 0.08838834764831845f) : 1.0f;
#pragma unroll
  for (int j = 0; j < 4; j++) {
    int id = tid + 256 * j;
    int k = id >> 3;
    int nn = (id & 7) * 4;
    float4 v = *(const float4*)(W + (size_t)(k0 + k) * D_ + n0 + nn);
    Tls[nn + 0][k] = f2b(v.x * scale);
    Tls[nn + 1][k] = f2b(v.y * scale);
    Tls[nn + 2][k] = f2b(v.z * scale);
    Tls[nn + 3][k] = f2b(v.w * scale);
  }
  __syncthreads();
#pragma unroll
  for (int j = 0; j < 2; j++) {
    int id = tid + 256 * j;
    int n = id >> 4;
    int seg = id & 15;
    short8 o = *(const short8*)&Tls[n][seg * 8];
    *(short8*)&Wt3[(size_t)w * D_ * E_ + (size_t)(n0 + n) * E_ + k0 + seg * 8] = o;
  }
}

// ---------------------------------------------------------------------------
// Kernel 2: fused QKV. Tile 64 tok x 192 ch, BK=64, 16 iters; grid 512 x 256
// thr, 34 KB LDS -> 4 blocks/CU capacity (2 resident).
// (a) g decoded as blockIdx>>8 so the two blocks sharing the same X rows land
// on the SAME XCD (256 % 8 == 0) -> second X read hits L2;
// (b) X->LDS bf16 staging via v_cvt_pk_bf16_f32 (2 instr/float4 vs ~20).
// ---------------------------------------------------------------------------
#define XLD 72  // 64 + 8 pad (shorts)

__global__ __launch_bounds__(256) void qkv_kernel(
    const float* __restrict__ X, const unsigned short* __restrict__ Wt3,
    unsigned short* __restrict__ Qf, unsigned short* __restrict__ Kf,
    unsigned short* __restrict__ Vf) {
  __shared__ __align__(16) unsigned short Xs[64 * XLD];   // 9.2 KB
  __shared__ __align__(16) unsigned short Ws[192 * 64];   // 24 KB swizzled
  const int tid = threadIdx.x;
  const int wv = tid >> 6;
  const int lane = tid & 63;
  const int l16 = lane & 15;
  const int quad = lane >> 4;
  const int wm = wv & 1;
  const int wn = wv >> 1;

  const int g = blockIdx.x >> 8;           // same-X pair lands on same XCD
  const int m0 = (blockIdx.x & 255) * 64;
  const unsigned short* Wg = Wt3 + (size_t)g * 192 * E_;

  const int xrow = tid >> 2;
  const int xq = (tid & 3) * 16;
  const int wrow_off = lane >> 3;
  const int wslot = lane & 7;

  floatx4 acc[2][6];
#pragma unroll
  for (int mt = 0; mt < 2; mt++)
#pragma unroll
    for (int nt = 0; nt < 6; nt++) acc[mt][nt] = (floatx4){0.f, 0.f, 0.f, 0.f};

  float4 xr[4];
#pragma unroll
  for (int c = 0; c < 4; c++)
    xr[c] = *(const float4*)(X + (size_t)(m0 + xrow) * E_ + xq + c * 4);

  for (int i = 0; i < 16; i++) {
    if (i) __syncthreads();
    const int k0 = i * 64;
#pragma unroll
    for (int c = 0; c < 4; c++) {
      uint2v pk;
      pk.x = cvtpk_bf16(xr[c].x, xr[c].y);
      pk.y = cvtpk_bf16(xr[c].z, xr[c].w);
      *(uint2v*)&Xs[xrow * XLD + xq + c * 4] = pk;
    }
#pragma unroll
    for (int j = 0; j < 6; j++) {
      int rbase = wv * 48 + j * 8;
      int row = rbase + wrow_off;
      int gseg = wslot ^ (row & 7);
      gl_lds16(Wg + (size_t)row * E_ + k0 + gseg * 8, &Ws[rbase * 64]);
    }
    __syncthreads();
    if (i < 15) {
#pragma unroll
      for (int c = 0; c < 4; c++)
        xr[c] = *(const float4*)(X + (size_t)(m0 + xrow) * E_ + k0 + 64 + xq + c * 4);
    }
    short8 af[2][2];
#pragma unroll
    for (int mt = 0; mt < 2; mt++)
#pragma unroll
      for (int kf = 0; kf < 2; kf++)
        af[mt][kf] = *(const short8*)&Xs[(wm * 32 + mt * 16 + l16) * XLD + kf * 32 + quad * 8];
#pragma unroll
    for (int nt = 0; nt < 6; nt++) {
      int n = wn * 96 + nt * 16 + l16;
#pragma unroll
      for (int kf = 0; kf < 2; kf++) {
        short8 bf = *(const short8*)&Ws[n * 64 + ((kf * 4 + quad) ^ (n & 7)) * 8];
        acc[0][nt] = __builtin_amdgcn_mfma_f32_16x16x32_bf16(af[0][kf], bf, acc[0][nt], 0, 0, 0);
        acc[1][nt] = __builtin_amdgcn_mfma_f32_16x16x32_bf16(af[1][kf], bf, acc[1][nt], 0, 0, 0);
      }
    }
  }

  // Epilogue -> fragment-packed outputs. C/D: col(n)=l16, row(m)=quad*4+r.
#pragma unroll
  for (int mt = 0; mt < 2; mt++)
#pragma unroll
    for (int nt = 0; nt < 6; nt++) {
      int n = g * 192 + wn * 96 + nt * 16 + l16;
      int t0 = m0 + wm * 32 + mt * 16 + quad * 4;
      int b = t0 >> 11;
      int tt0 = t0 & (T_ - 1);
      int tile = tt0 >> 5;
      if (n < 256) {
        unsigned short* Fg = (n < 128) ? Qf : Kf;
        int d = n & 127;
        int kf = d >> 4;
        int hi2 = (d >> 3) & 1;
        int j = d & 7;
        int l32b = tt0 & 31;  // + r
        size_t base = ((size_t)((b * 64 + tile) * 8 + kf)) * 512 + hi2 * 256 + j;
#pragma unroll
        for (int r = 0; r < 4; r++)
          Fg[base + (size_t)(l32b + r) * 8] = f2b(acc[mt][nt][r]);
      } else {
        int d = n - 256;
        int k2 = (tt0 >> 4) & 1;
        int hi2 = (tt0 >> 3) & 1;
        int jb = tt0 & 7;  // 0 or 4; +r contiguous
        int l32 = d & 31;
        int dt = d >> 5;
        size_t base = ((size_t)((b * 64 + tile) * 8 + k2 * 4 + dt)) * 512 +
                      (size_t)(hi2 * 32 + l32) * 8 + jb;
        uint2v pv;
        pv.x = cvtpk_bf16(acc[mt][nt][0], acc[mt][nt][1]);
        pv.y = cvtpk_bf16(acc[mt][nt][2], acc[mt][nt][3]);
        *(uint2v*)&Vf[base] = pv;
      }
    }
}

// ---------------------------------------------------------------------------
// Kernel 3: causal flash attention — frag-packed register-direct, barrier-free
// K-loop with manual K-prefetch. Softmax de-VALU-ification:
//  - T13 defer-max (THR=8): alpha rescale (exp2 + 64 oacc mults) runs rarely;
//    p <= 2^8 is bf16/f32-safe. Guard: mnew = fmax(mval,mx) computed ALWAYS
//    so mval can never stay at -1e30 while exp2 runs.
//  - T12 pack: 8x v_cvt_pk_bf16_f32 + 4x permlane32_swap (builtin) replace
//    16 f2b + 8 shl/or + 8 ds_bpermute + 16 cndmask.
//  - cross-half max via permlane32_swap; cross-half l-sum hoisted out of loop.
// ---------------------------------------------------------------------------
#define LOADK(DST, ITV)                                                      \
  _Pragma("unroll") for (int kf_ = 0; kf_ < 8; kf_++)                        \
      DST[kf_] = *(const short8*)(Kbase + (size_t)(ITV) * 4096 + kf_ * 512 + lane * 8);

#define LOADV(DST, ITV)                                                      \
  _Pragma("unroll") for (int f_ = 0; f_ < 8; f_++)                           \
      DST[f_] = *(const short8*)(Vbase + (size_t)(ITV) * 4096 + f_ * 512 + lane * 8);

#define ATTN_STEP(KFR, VFR, ITV)                                             \
  {                                                                          \
    floatx16 sacc;                                                           \
    _Pragma("unroll") for (int r = 0; r < 16; r++) sacc[r] = 0.f;            \
    _Pragma("unroll") for (int kf = 0; kf < 8; kf++)                         \
        sacc = __builtin_amdgcn_mfma_f32_32x32x16_bf16(KFR[kf], qf[kf], sacc, 0, 0, 0); \
    if ((ITV) == qt) {                                                       \
      _Pragma("unroll") for (int r = 0; r < 16; r++) {                       \
        int kv = (ITV) * 32 + (r & 3) + 8 * (r >> 2) + 4 * hi;               \
        if (kv > qg) sacc[r] = -1e30f;                                       \
      }                                                                      \
    }                                                                        \
    float mx = fmaxf(                                                        \
        fmaxf(fmaxf(fmaxf(sacc[0], sacc[1]), fmaxf(sacc[2], sacc[3])),       \
              fmaxf(fmaxf(sacc[4], sacc[5]), fmaxf(sacc[6], sacc[7]))),      \
        fmaxf(fmaxf(fmaxf(sacc[8], sacc[9]), fmaxf(sacc[10], sacc[11])),     \
              fmaxf(fmaxf(sacc[12], sacc[13]), fmaxf(sacc[14], sacc[15])))); \
    mx = xhalf_max(mx);                                                      \
    float mnew = fmaxf(mval, mx);                                            \
    if (__any((mnew - mval) > 8.f)) {                                        \
      float alpha = EXP2F(mval - mnew);                                      \
      mval = mnew;                                                           \
      lval *= alpha;                                                         \
      _Pragma("unroll") for (int dt = 0; dt < 4; dt++)                       \
          _Pragma("unroll") for (int r = 0; r < 16; r++) oacc[dt][r] *= alpha; \
    }                                                                        \
    _Pragma("unroll") for (int r = 0; r < 16; r++)                           \
        sacc[r] = EXP2F(sacc[r] - mval);                                     \
    lval += (((sacc[0] + sacc[1]) + (sacc[2] + sacc[3])) +                   \
             ((sacc[4] + sacc[5]) + (sacc[6] + sacc[7]))) +                  \
            (((sacc[8] + sacc[9]) + (sacc[10] + sacc[11])) +                 \
             ((sacc[12] + sacc[13]) + (sacc[14] + sacc[15])));               \
    unsigned int c0_ = cvtpk_bf16(sacc[0], sacc[1]);                         \
    unsigned int c1_ = cvtpk_bf16(sacc[2], sacc[3]);                         \
    unsigned int c2_ = cvtpk_bf16(sacc[4], sacc[5]);                         \
    unsigned int c3_ = cvtpk_bf16(sacc[6], sacc[7]);                         \
    unsigned int c4_ = cvtpk_bf16(sacc[8], sacc[9]);                         \
    unsigned int c5_ = cvtpk_bf16(sacc[10], sacc[11]);                       \
    unsigned int c6_ = cvtpk_bf16(sacc[12], sacc[13]);                       \
    unsigned int c7_ = cvtpk_bf16(sacc[14], sacc[15]);                       \
    PLSWAP(c0_, c2_);                                                        \
    PLSWAP(c1_, c3_);                                                        \
    PLSWAP(c4_, c6_);                                                        \
    PLSWAP(c5_, c7_);                                                        \
    union { short8 s; unsigned int u[4]; } pf0, pf1;                         \
    pf0.u[0] = c0_; pf0.u[1] = c1_; pf0.u[2] = c2_; pf0.u[3] = c3_;          \
    pf1.u[0] = c4_; pf1.u[1] = c5_; pf1.u[2] = c6_; pf1.u[3] = c7_;          \
    _Pragma("unroll") for (int dt = 0; dt < 4; dt++) {                       \
      oacc[dt] = __builtin_amdgcn_mfma_f32_32x32x16_bf16(VFR[dt], pf0.s, oacc[dt], 0, 0, 0);     \
      oacc[dt] = __builtin_amdgcn_mfma_f32_32x32x16_bf16(VFR[4 + dt], pf1.s, oacc[dt], 0, 0, 0); \
    }                                                                        \
  }

__global__ __launch_bounds__(256, 2) void attn_kernel(
    const unsigned short* __restrict__ Qf, const unsigned short* __restrict__ Kf,
    const unsigned short* __restrict__ Vf, float* __restrict__ Out) {
  __shared__ float Om[3][128][32];  // 48 KB merge buffer
  __shared__ float Ms[4][32], Ls[4][32];

  const int tid = threadIdx.x;
  const int wv = tid >> 6;
  const int lane = tid & 63;
  const int l32 = lane & 31;
  const int hi = lane >> 5;

  const int batch = blockIdx.x & 7;
  const int qt = 63 - (blockIdx.x >> 3);  // longest-first
  const int qb = qt * 32;
  const int qg = qb + l32;

  const unsigned short* Kbase = Kf + (size_t)batch * 64 * 4096;
  const unsigned short* Vbase = Vf + (size_t)batch * 64 * 4096;

  // Q B-frags: coalesced base+lane*16
  short8 qf[8];
  const unsigned short* Qp = Qf + (size_t)(batch * 64 + qt) * 4096;
#pragma unroll
  for (int kf = 0; kf < 8; kf++)
    qf[kf] = *(const short8*)(Qp + kf * 512 + lane * 8);

  floatx16 oacc[4];  // O^T: col q=l32, row d=dt*32+(r&3)+8*(r>>2)+4*hi
#pragma unroll
  for (int dt = 0; dt < 4; dt++)
#pragma unroll
    for (int r = 0; r < 16; r++) oacc[dt][r] = 0.f;
  float mval = -1e30f, lval = 0.f;

  short8 kA[8], kB[8], vC[8];
  int it = wv;
  if (it <= qt) {
    LOADK(kA, it);
    while (true) {
      int nit = it + 4;
      LOADV(vC, it);
      if (nit <= qt) LOADK(kB, nit);
      ATTN_STEP(kA, vC, it);
      if (nit > qt) break;
      it = nit;
      nit = it + 4;
      LOADV(vC, it);
      if (nit <= qt) LOADK(kA, nit);
      ATTN_STEP(kB, vC, it);
      if (nit > qt) break;
      it = nit;
    }
  }
  // per-half partial l -> full l (was per-step shfl_xor; now once)
  lval = xhalf_sum(lval);

  // merge 4 partials: waves 1-3 publish (m,l,O) to LDS; wave 0 combines.
  if (wv) {
    if (hi == 0) { Ms[wv][l32] = mval; Ls[wv][l32] = lval; }
#pragma unroll
    for (int dt = 0; dt < 4; dt++)
#pragma unroll
      for (int r = 0; r < 16; r++) {
        int d = dt * 32 + (r & 3) + 8 * (r >> 2) + 4 * hi;
        Om[wv - 1][d][l32] = oacc[dt][r];
      }
  }
  __syncthreads();
  if (wv == 0) {
    float m1 = Ms[1][l32], m2 = Ms[2][l32], m3 = Ms[3][l32];
    float l1 = Ls[1][l32], l2 = Ls[2][l32], l3 = Ls[3][l32];
    float mstar = fmaxf(fmaxf(mval, m1), fmaxf(m2, m3));
    float a0 = EXP2F(mval - mstar);
    float a1 = EXP2F(m1 - mstar);
    float a2 = EXP2F(m2 - mstar);
    float a3 = EXP2F(m3 - mstar);
    float linv = 1.f / (lval * a0 + l1 * a1 + l2 * a2 + l3 * a3);
    float* Og = Out + ((size_t)batch * T_ + qg) * D_;
#pragma unroll
    for (int dt = 0; dt < 4; dt++)
#pragma unroll
      for (int rg = 0; rg < 4; rg++) {
        int dbase = dt * 32 + 8 * rg + 4 * hi;
        float4 o;
#pragma unroll
        for (int c = 0; c < 4; c++) {
          float v = oacc[dt][rg * 4 + c] * a0 +
                    Om[0][dbase + c][l32] * a1 +
                    Om[1][dbase + c][l32] * a2 +
                    Om[2][dbase + c][l32] * a3;
          ((float*)&o)[c] = v * linv;
        }
        *(float4*)&Og[dbase] = o;
      }
  }
}

// ---------------------------------------------------------------------------
extern "C" void kernel_launch(void* const* d_in, const int* in_sizes, int n_in,
                              void* d_out, int out_size, void* d_ws, size_t ws_size,
                              hipStream_t stream) {
  const float* X  = (const float*)d_in[0];
  const float* Wq = (const float*)d_in[1];
  const float* Wk = (const float*)d_in[2];
  const float* Wv = (const float*)d_in[3];
  float* Out = (float*)d_out;

  char* ws = (char*)d_ws;
  unsigned short* Wt3 = (unsigned short*)(ws);                        // 768 KB
  unsigned short* Qf  = (unsigned short*)(ws + 786432);               // 4 MB
  unsigned short* Kf  = (unsigned short*)(ws + 786432 + 4194304);     // 4 MB
  unsigned short* Vf  = (unsigned short*)(ws + 786432 + 2 * 4194304); // 4 MB

  hipLaunchKernelGGL(wtrans_kernel, dim3(96), dim3(256), 0, stream, Wq, Wk, Wv, Wt3);
  hipLaunchKernelGGL(qkv_kernel, dim3(512), dim3(256), 0, stream, X, Wt3, Qf, Kf, Vf);
  hipLaunchKernelGGL(attn_kernel, dim3(512), dim3(256), 0, stream, Qf, Kf, Vf, Out);
}